// Round 11
// baseline (29.758 us; speedup 1.0000x reference)
//
#include <hip/hip_runtime.h>
#include <hip/hip_bf16.h>
#include <math.h>

// Problem constants (from reference)
#define NB     128
#define NT_ALL 197
#define NT     196
#define ND     768
#define NORG   5
#define NE     8
#define NCLS   100
#define NCOL   105            // 100 cls + 5 aux columns
#define NTOK   (NB * NT)      // 25088
#define KB     24             // 768 / 32 k-blocks total
#define KQ     6              // k-blocks per wave (K split across 4 waves)

#define RBLKS  1568           // router blocks: 1568 * 16 tokens = 25088
#define CBLKS  256            // cls blocks after

typedef short  bf16x8 __attribute__((ext_vector_type(8)));
typedef float  f32x4  __attribute__((ext_vector_type(4)));

// Output layout (flat, concatenated in return order):
//   logits  : NB*NCLS = 12800   @ 0
//   aux_org : NB*NORG = 640     @ 12800
//   probs   : NTOK*NE = 200704  @ 13440
//   entropy : NTOK    = 25088   @ 214144

struct SharedRouter {
    float x[16 * ND];                     // 48 KB token tile, f32, LINEAR (DMA)
    __hip_bfloat16 a[KB * 4 * 16 * 8];    // 24 KB weight A-fragments
    float acc[3][64][4];                  // partial accs from waves 1..3
    float pl[2][NE];
};
struct SharedCls {
    float x[ND];
    float red[4];
    float part[4][65];
};

// Async global->LDS DMA, 16B per lane. LDS dest = wave-uniform base + lane*16
// (HW adds the lane offset); global src is PER-LANE (pre-swizzled by caller).
__device__ __forceinline__ void dma16(const void* g, void* l) {
    __builtin_amdgcn_global_load_lds(
        (const __attribute__((address_space(1))) void*)g,
        (__attribute__((address_space(3))) void*)l,
        16, 0, 0);
}

// ---------------------------------------------------------------------------
// Router: 16 consecutive tokens per block. X staged f32 via 12 back-to-back
// global_load_lds per wave (deep outstanding-load queue, zero VGPR cost),
// with a both-sides XOR swizzle (src-global ^ ((tt&7)<<4), same on LDS read)
// to kill the 16-way ds_read bank conflict of the 3072B row stride.
// MFMA K-loop: wave w owns k-blocks [w*6, w*6+6); partials combined via LDS.
// ---------------------------------------------------------------------------
__global__ __launch_bounds__(256, 2) void fused_kernel(
    const float* __restrict__ tokens,    // (NB, NT_ALL, ND)
    const float* __restrict__ priors,    // (NB, NORG)
    const float* __restrict__ rw,        // (ND+NORG, NE) row-major
    const float* __restrict__ rbias,     // (NE,)
    const float* __restrict__ ln_g, const float* __restrict__ ln_b,
    const float* __restrict__ cls_w,     // (ND, NCLS)
    const float* __restrict__ cls_b,     // (NCLS,)
    const float* __restrict__ aux_w,     // (ND, NORG)
    const float* __restrict__ aux_b,     // (NORG,)
    float* __restrict__ out_logits,      // (NB, NCLS)
    float* __restrict__ out_aux,         // (NB, NORG)
    float* __restrict__ probs_out,       // (NTOK, NE)
    float* __restrict__ ent_out)         // (NTOK,)
{
    __shared__ union { SharedRouter r; SharedCls c; } sm;
    const int t = threadIdx.x;

    if (blockIdx.x < RBLKS) {
        // ------------------------------ router ------------------------------
        const int wid  = t >> 6;
        const int lane = t & 63;
        const int tok0 = blockIdx.x * 16;

        // ---- X staging: wave wid owns local tokens wid*4..wid*4+3,
        //      3 chunks of 1KB per token row; 12 DMA instrs back-to-back.
#pragma unroll
        for (int i = 0; i < 12; ++i) {
            const int ltt = wid * 4 + i / 3;          // local token 0..15
            const int s0  = (i % 3) * 1024;           // byte offset in row
            const int gt  = tok0 + ltt;
            const int bb  = gt / NT;
            const size_t rowb = (size_t)(gt + bb + 1) * (ND * 4);
            // per-lane source, pre-swizzled (involution within 128B blocks)
            const int soff = (s0 + lane * 16) ^ ((ltt & 7) << 4);
            dma16((const char*)tokens + rowb + soff,
                  (char*)sm.r.x + ltt * 3072 + s0);   // uniform chunk base
        }

        // ---- W staging (overlaps DMA flight): zero-pad rows e>=8 ----
        {
            bf16x8 z = {0, 0, 0, 0, 0, 0, 0, 0};
            bf16x8* p = (bf16x8*)sm.r.a;
            for (int i = t; i < KB * 4 * 8; i += 256)
                p[(i >> 3) * 16 + 8 + (i & 7)] = z;
        }
        // fill e<8: one k-row (8 experts) per thread-iter, 3 iters
        for (int k = t; k < ND; k += 256) {
            const float4 w0 = *reinterpret_cast<const float4*>(rw + k * 8);
            const float4 w1 = *reinterpret_cast<const float4*>(rw + k * 8 + 4);
            const int kb = k >> 5, gg = (k >> 3) & 3, j = k & 7;
            __hip_bfloat16* dst = &sm.r.a[((kb * 4 + gg) * 16) * 8 + j];
            dst[0 * 8] = __float2bfloat16(w0.x);
            dst[1 * 8] = __float2bfloat16(w0.y);
            dst[2 * 8] = __float2bfloat16(w0.z);
            dst[3 * 8] = __float2bfloat16(w0.w);
            dst[4 * 8] = __float2bfloat16(w1.x);
            dst[5 * 8] = __float2bfloat16(w1.y);
            dst[6 * 8] = __float2bfloat16(w1.z);
            dst[7 * 8] = __float2bfloat16(w1.w);
        }
        // Prior+bias logits for the (at most 2) batch rows this block spans.
        const int b0 = tok0 / NT;
        const int b1 = (tok0 + 15) / NT;
        if (t < 16) {
            const int e = t & 7, which = t >> 3;
            const int bb = which ? b1 : b0;
            float a = rbias[e];
#pragma unroll
            for (int o = 0; o < NORG; ++o)
                a = fmaf(priors[bb * NORG + o], rw[(ND + o) * NE + e], a);
            sm.r.pl[which][e] = a;
        }
        __syncthreads();   // drains vmcnt(0): DMA + w staging complete

        // ---- Compute: wave wid owns k-blocks wid*6..wid*6+5 ----
        const int tt  = lane & 15;
        const int g   = lane >> 4;
        const int swz = (tt & 7) << 4;
        const char* xbase = (const char*)sm.r.x + tt * 3072;
        const bf16x8* s_a8 = (const bf16x8*)sm.r.a;

        f32x4 acc0 = {0.f, 0.f, 0.f, 0.f};
        f32x4 acc1 = {0.f, 0.f, 0.f, 0.f};
#pragma unroll
        for (int k = 0; k < KQ; ++k) {
            const int kb   = wid * KQ + k;
            const int koff = kb * 128 + g * 32;
            const f32x4 xa = *reinterpret_cast<const f32x4*>(xbase + (koff ^ swz));
            const f32x4 xc = *reinterpret_cast<const f32x4*>(xbase + ((koff + 16) ^ swz));
            union { bf16x8 v; __hip_bfloat16 h[8]; } u;
            u.h[0] = __float2bfloat16(xa[0]);
            u.h[1] = __float2bfloat16(xa[1]);
            u.h[2] = __float2bfloat16(xa[2]);
            u.h[3] = __float2bfloat16(xa[3]);
            u.h[4] = __float2bfloat16(xc[0]);
            u.h[5] = __float2bfloat16(xc[1]);
            u.h[6] = __float2bfloat16(xc[2]);
            u.h[7] = __float2bfloat16(xc[3]);
            const bf16x8 af = s_a8[(kb * 4 + g) * 16 + tt];
            if (k & 1)
                acc1 = __builtin_amdgcn_mfma_f32_16x16x32_bf16(af, u.v, acc1, 0, 0, 0);
            else
                acc0 = __builtin_amdgcn_mfma_f32_16x16x32_bf16(af, u.v, acc0, 0, 0, 0);
        }
        f32x4 acc = acc0 + acc1;

        // Combine K-quarters: waves 1..3 publish, wave 0 finishes.
        if (wid > 0)
            *reinterpret_cast<f32x4*>(&sm.r.acc[wid - 1][lane][0]) = acc;
        __syncthreads();

        if (wid == 0) {
            acc += *reinterpret_cast<const f32x4*>(&sm.r.acc[0][lane][0]);
            acc += *reinterpret_cast<const f32x4*>(&sm.r.acc[1][lane][0]);
            acc += *reinterpret_cast<const f32x4*>(&sm.r.acc[2][lane][0]);

            // Gather the other 4 experts from lane^16.
            const float p0 = __shfl_xor(acc[0], 16, 64);
            const float p1 = __shfl_xor(acc[1], 16, 64);
            const float p2 = __shfl_xor(acc[2], 16, 64);
            const float p3 = __shfl_xor(acc[3], 16, 64);

            if (lane < 16) {
                const int token = tok0 + tt;
                const int b = token / NT;
                float lg[NE] = {acc[0], acc[1], acc[2], acc[3], p0, p1, p2, p3};
                const int bsel = (b == b0) ? 0 : 1;
#pragma unroll
                for (int e = 0; e < NE; ++e) lg[e] += sm.r.pl[bsel][e];

                // softmax + entropy: ent = ln(S) - (sum p*l)/S, l = logit-max
                float m = lg[0];
#pragma unroll
                for (int e = 1; e < NE; ++e) m = fmaxf(m, lg[e]);
                float S = 0.f, dd = 0.f;
#pragma unroll
                for (int e = 0; e < NE; ++e) {
                    const float l = lg[e] - m;
                    const float p = __expf(l);
                    lg[e] = p;
                    S += p;
                    dd = fmaf(p, l, dd);
                }
                const float inv = 1.f / S;
                const float ent = __logf(S) - dd * inv;

                float4 q0 = {lg[0] * inv, lg[1] * inv, lg[2] * inv, lg[3] * inv};
                float4 q1 = {lg[4] * inv, lg[5] * inv, lg[6] * inv, lg[7] * inv};
                *reinterpret_cast<float4*>(probs_out + (size_t)token * NE)     = q0;
                *reinterpret_cast<float4*>(probs_out + (size_t)token * NE + 4) = q1;
                ent_out[token] = ent;
            }
        }
    } else {
        // ------------------------------ CLS head ----------------------------
        const int cb   = blockIdx.x - RBLKS;     // 0..255
        const int b    = cb >> 1;
        const int half = cb & 1;
        const int lane = t & 63;
        const int wv   = t >> 6;                 // 0..3

        const float* xp = tokens + (size_t)b * NT_ALL * ND;  // cls token

        float sum = 0.f;
        for (int i = t; i < ND; i += 256) { float v = xp[i]; sm.c.x[i] = v; sum += v; }
#pragma unroll
        for (int off = 32; off; off >>= 1) sum += __shfl_xor(sum, off, 64);
        if (lane == 0) sm.c.red[wv] = sum;
        __syncthreads();
        const float mu = (sm.c.red[0] + sm.c.red[1] + sm.c.red[2] + sm.c.red[3]) * (1.f / ND);
        __syncthreads();

        float sq = 0.f;
        for (int i = t; i < ND; i += 256) { float d = sm.c.x[i] - mu; sq += d * d; }
#pragma unroll
        for (int off = 32; off; off >>= 1) sq += __shfl_xor(sq, off, 64);
        if (lane == 0) sm.c.red[wv] = sq;
        __syncthreads();
        const float var  = (sm.c.red[0] + sm.c.red[1] + sm.c.red[2] + sm.c.red[3]) * (1.f / ND);
        const float rstd = rsqrtf(var + 1e-5f);
        __syncthreads();

        for (int i = t; i < ND; i += 256)
            sm.c.x[i] = (sm.c.x[i] - mu) * rstd * ln_g[i] + ln_b[i];
        __syncthreads();

        const int c = half * 64 + lane;
        const float* wp; int st;
        if (c < NCLS)      { wp = cls_w + c;          st = NCLS; }
        else if (c < NCOL) { wp = aux_w + (c - NCLS); st = NORG; }
        else               { wp = aux_w;              st = NORG; }

        const int d0 = wv * 192;
        const float* w = wp + (size_t)d0 * st;
        const int st2 = 2 * st, st3 = 3 * st, st4 = 4 * st;
        float a0 = 0.f, a1 = 0.f, a2 = 0.f, a3 = 0.f;
#pragma unroll 8
        for (int j = 0; j < 192; j += 4) {
            const float4 x4 = *reinterpret_cast<const float4*>(&sm.c.x[d0 + j]);
            a0 = fmaf(x4.x, w[0],   a0);
            a1 = fmaf(x4.y, w[st],  a1);
            a2 = fmaf(x4.z, w[st2], a2);
            a3 = fmaf(x4.w, w[st3], a3);
            w += st4;
        }
        sm.c.part[wv][lane] = (a0 + a1) + (a2 + a3);
        __syncthreads();

        if (t < 64) {
            float r = sm.c.part[0][t] + sm.c.part[1][t] + sm.c.part[2][t] + sm.c.part[3][t];
            const int cc = half * 64 + t;
            if (cc < NCLS)
                out_logits[b * NCLS + cc] = r + cls_b[cc];
            else if (cc < NCOL)
                out_aux[b * NORG + (cc - NCLS)] = r + aux_b[cc - NCLS];
        }
    }
}

extern "C" void kernel_launch(void* const* d_in, const int* in_sizes, int n_in,
                              void* d_out, int out_size, void* d_ws, size_t ws_size,
                              hipStream_t stream) {
    const float* tokens = (const float*)d_in[0];
    const float* priors = (const float*)d_in[1];
    const float* rw     = (const float*)d_in[2];
    const float* rbias  = (const float*)d_in[3];
    // d_in[4..7] = w1,b1,w2,b2 : dead code (MoE output unused by reference)
    const float* ln_g   = (const float*)d_in[8];
    const float* ln_b   = (const float*)d_in[9];
    const float* cls_w  = (const float*)d_in[10];
    const float* cls_b  = (const float*)d_in[11];
    const float* aux_w  = (const float*)d_in[12];
    const float* aux_b  = (const float*)d_in[13];

    float* out = (float*)d_out;
    float* out_logits = out;                                   // 12800
    float* out_aux    = out + NB * NCLS;                       // +640
    float* out_probs  = out + NB * NCLS + NB * NORG;           // +200704
    float* out_ent    = out + NB * NCLS + NB * NORG + (size_t)NTOK * NE;

    fused_kernel<<<RBLKS + CBLKS, 256, 0, stream>>>(
        tokens, priors, rw, rbias, ln_g, ln_b, cls_w, cls_b, aux_w, aux_b,
        out_logits, out_aux, out_probs, out_ent);
}

// Round 13
// 28.495 us; speedup vs baseline: 1.0443x; 1.0443x over previous
//
#include <hip/hip_runtime.h>
#include <hip/hip_bf16.h>
#include <math.h>

// Problem constants (from reference)
#define NB     128
#define NT_ALL 197
#define NT     196
#define ND     768
#define NORG   5
#define NE     8
#define NCLS   100
#define NCOL   105            // 100 cls + 5 aux columns
#define NTOK   (NB * NT)      // 25088
#define KB     24             // 768 / 32 k-blocks total
#define PF     6              // x-prefetch ring depth

#define RBLKS  392            // router blocks FIRST: 392 * 4 waves * 16 tokens
#define CBLKS  256            // cls blocks after

typedef short  bf16x8 __attribute__((ext_vector_type(8)));
typedef float  f32x4  __attribute__((ext_vector_type(4)));

// Output layout (flat, concatenated in return order):
//   logits  : NB*NCLS = 12800   @ 0
//   aux_org : NB*NORG = 640     @ 12800
//   probs   : NTOK*NE = 200704  @ 13440
//   entropy : NTOK    = 25088   @ 214144

// ---------------------------------------------------------------------------
// Router-as-GEMM (best variant, R6 structure): one wave owns 16 tokens, full
// K=768; A = W^T staged once per block in LDS as MFMA fragments; x read
// direct-to-register through a PF-deep ring with NONTEMPORAL loads (tokens
// are read-once: nt avoids polluting the per-XCD L2 that the weight table
// and rw re-reads live in). Router blocks first; cls tail fills behind.
// ---------------------------------------------------------------------------
__global__ __launch_bounds__(256, 4) void fused_kernel(
    const float* __restrict__ tokens,    // (NB, NT_ALL, ND)
    const float* __restrict__ priors,    // (NB, NORG)
    const float* __restrict__ rw,        // (ND+NORG, NE) row-major
    const float* __restrict__ rbias,     // (NE,)
    const float* __restrict__ ln_g, const float* __restrict__ ln_b,
    const float* __restrict__ cls_w,     // (ND, NCLS)
    const float* __restrict__ cls_b,     // (NCLS,)
    const float* __restrict__ aux_w,     // (ND, NORG)
    const float* __restrict__ aux_b,     // (NORG,)
    float* __restrict__ out_logits,      // (NB, NCLS)
    float* __restrict__ out_aux,         // (NB, NORG)
    float* __restrict__ probs_out,       // (NTOK, NE)
    float* __restrict__ ent_out)         // (NTOK,)
{
    const int t = threadIdx.x;

    if (blockIdx.x < RBLKS) {
        // ------------------------------ router ------------------------------
        __shared__ __align__(16) __hip_bfloat16 s_a[KB * 4 * 16 * 8]; // 24KB
        __shared__ float s_pl[2][NE];

        const int wid  = t >> 6;
        const int lane = t & 63;
        const int tok0 = blockIdx.x * 64;
        const int gbase = tok0 + wid * 16;        // this wave's 16 tokens
        const int tt = lane & 15;                 // token col / expert row
        const int g  = lane >> 4;                 // k-octet selector
        const int token = gbase + tt;
        const int b  = token / NT;
        const float* xp = tokens + ((size_t)b * NT_ALL + 1 + (token - b * NT)) * ND
                          + g * 8;

        // Prologue x-prefetch ring (nontemporal: read-once stream).
        f32x4 xb[PF][2];
#pragma unroll
        for (int i = 0; i < PF; ++i) {
            xb[i][0] = __builtin_nontemporal_load(
                reinterpret_cast<const f32x4*>(xp + i * 32));
            xb[i][1] = __builtin_nontemporal_load(
                reinterpret_cast<const f32x4*>(xp + i * 32 + 4));
        }

        // Zero-init ONLY the e>=8 padding rows (disjoint from fill below).
        {
            bf16x8 z = {0, 0, 0, 0, 0, 0, 0, 0};
            bf16x8* p = (bf16x8*)s_a;
            for (int i = t; i < KB * 4 * 8; i += 256)
                p[(i >> 3) * 16 + 8 + (i & 7)] = z;
        }
        // Fill real experts (e<8): coalesced rw reads, scattered b16 writes.
        for (int i = t; i < ND * NE; i += 256) {
            const int k = i >> 3, e = i & 7;
            const int kb = k >> 5, gg = (k >> 3) & 3, j = k & 7;
            s_a[(((kb * 4 + gg) * 16) + e) * 8 + j] = __float2bfloat16(rw[i]);
        }
        // Prior+bias logits for the (at most 2) batch rows this block spans.
        const int b0 = tok0 / NT;
        const int b1 = (tok0 + 63) / NT;
        if (t < 16) {
            const int e = t & 7, which = t >> 3;
            const int bb = which ? b1 : b0;
            float a = rbias[e];
#pragma unroll
            for (int o = 0; o < NORG; ++o)
                a = fmaf(priors[bb * NORG + o], rw[(ND + o) * NE + e], a);
            s_pl[which][e] = a;
        }
        __syncthreads();   // staging complete

        const bf16x8* s_a8 = (const bf16x8*)s_a;
        f32x4 acc0 = {0.f, 0.f, 0.f, 0.f};
        f32x4 acc1 = {0.f, 0.f, 0.f, 0.f};

#pragma unroll
        for (int kb = 0; kb < KB; ++kb) {
            const f32x4 x0 = xb[kb % PF][0];
            const f32x4 x1 = xb[kb % PF][1];
            union { bf16x8 v; __hip_bfloat16 h[8]; } u;
            u.h[0] = __float2bfloat16(x0[0]);
            u.h[1] = __float2bfloat16(x0[1]);
            u.h[2] = __float2bfloat16(x0[2]);
            u.h[3] = __float2bfloat16(x0[3]);
            u.h[4] = __float2bfloat16(x1[0]);
            u.h[5] = __float2bfloat16(x1[1]);
            u.h[6] = __float2bfloat16(x1[2]);
            u.h[7] = __float2bfloat16(x1[3]);
            const bf16x8 af = s_a8[(kb * 4 + g) * 16 + tt];
            if (kb & 1)
                acc1 = __builtin_amdgcn_mfma_f32_16x16x32_bf16(af, u.v, acc1, 0, 0, 0);
            else
                acc0 = __builtin_amdgcn_mfma_f32_16x16x32_bf16(af, u.v, acc0, 0, 0, 0);
            if (kb + PF < KB) {
                xb[kb % PF][0] = __builtin_nontemporal_load(
                    reinterpret_cast<const f32x4*>(xp + (kb + PF) * 32));
                xb[kb % PF][1] = __builtin_nontemporal_load(
                    reinterpret_cast<const f32x4*>(xp + (kb + PF) * 32 + 4));
            }
        }
        const f32x4 acc = acc0 + acc1;

        // Gather the other 4 experts from lane^16.
        const float p0 = __shfl_xor(acc[0], 16, 64);
        const float p1 = __shfl_xor(acc[1], 16, 64);
        const float p2 = __shfl_xor(acc[2], 16, 64);
        const float p3 = __shfl_xor(acc[3], 16, 64);

        if (lane < 16) {
            float lg[NE] = {acc[0], acc[1], acc[2], acc[3], p0, p1, p2, p3};
            const int bsel = (token >= (b0 + 1) * NT) ? 1 : 0;
#pragma unroll
            for (int e = 0; e < NE; ++e) lg[e] += s_pl[bsel][e];

            // softmax + entropy: ent = ln(S) - (sum p*l)/S, l = logit - max
            float m = lg[0];
#pragma unroll
            for (int e = 1; e < NE; ++e) m = fmaxf(m, lg[e]);
            float S = 0.f, dd = 0.f;
#pragma unroll
            for (int e = 0; e < NE; ++e) {
                const float l = lg[e] - m;
                const float p = __expf(l);
                lg[e] = p;
                S += p;
                dd = fmaf(p, l, dd);
            }
            const float inv = 1.f / S;
            const float ent = __logf(S) - dd * inv;

            float4 q0 = {lg[0] * inv, lg[1] * inv, lg[2] * inv, lg[3] * inv};
            float4 q1 = {lg[4] * inv, lg[5] * inv, lg[6] * inv, lg[7] * inv};
            *reinterpret_cast<float4*>(probs_out + (size_t)token * NE)     = q0;
            *reinterpret_cast<float4*>(probs_out + (size_t)token * NE + 4) = q1;
            ent_out[token] = ent;
        }
    } else {
        // ------------------------------ CLS head ----------------------------
        const int cb   = blockIdx.x - RBLKS;     // 0..255
        const int b    = cb >> 1;
        const int half = cb & 1;
        const int lane = t & 63;
        const int wv   = t >> 6;                 // 0..3

        __shared__ __align__(16) float s_x[ND];
        __shared__ float s_red[4];
        __shared__ float s_part[4][65];

        const float* xp = tokens + (size_t)b * NT_ALL * ND;  // cls token

        float sum = 0.f;
        for (int i = t; i < ND; i += 256) { float v = xp[i]; s_x[i] = v; sum += v; }
#pragma unroll
        for (int off = 32; off; off >>= 1) sum += __shfl_xor(sum, off, 64);
        if (lane == 0) s_red[wv] = sum;
        __syncthreads();
        const float mu = (s_red[0] + s_red[1] + s_red[2] + s_red[3]) * (1.f / ND);
        __syncthreads();

        float sq = 0.f;
        for (int i = t; i < ND; i += 256) { float d = s_x[i] - mu; sq += d * d; }
#pragma unroll
        for (int off = 32; off; off >>= 1) sq += __shfl_xor(sq, off, 64);
        if (lane == 0) s_red[wv] = sq;
        __syncthreads();
        const float var  = (s_red[0] + s_red[1] + s_red[2] + s_red[3]) * (1.f / ND);
        const float rstd = rsqrtf(var + 1e-5f);
        __syncthreads();

        for (int i = t; i < ND; i += 256)
            s_x[i] = (s_x[i] - mu) * rstd * ln_g[i] + ln_b[i];
        __syncthreads();

        const int c = half * 64 + lane;
        const float* wp; int st;
        if (c < NCLS)      { wp = cls_w + c;          st = NCLS; }
        else if (c < NCOL) { wp = aux_w + (c - NCLS); st = NORG; }
        else               { wp = aux_w;              st = NORG; }

        const int d0 = wv * 192;
        const float* w = wp + (size_t)d0 * st;
        const int st2 = 2 * st, st3 = 3 * st, st4 = 4 * st;
        float a0 = 0.f, a1 = 0.f, a2 = 0.f, a3 = 0.f;
#pragma unroll 8
        for (int j = 0; j < 192; j += 4) {
            const float4 x4 = *reinterpret_cast<const float4*>(&s_x[d0 + j]);
            a0 = fmaf(x4.x, w[0],   a0);
            a1 = fmaf(x4.y, w[st],  a1);
            a2 = fmaf(x4.z, w[st2], a2);
            a3 = fmaf(x4.w, w[st3], a3);
            w += st4;
        }
        s_part[wv][lane] = (a0 + a1) + (a2 + a3);
        __syncthreads();

        if (t < 64) {
            float r = s_part[0][t] + s_part[1][t] + s_part[2][t] + s_part[3][t];
            const int cc = half * 64 + t;
            if (cc < NCLS)
                out_logits[b * NCLS + cc] = r + cls_b[cc];
            else if (cc < NCOL)
                out_aux[b * NORG + (cc - NCLS)] = r + aux_b[cc - NCLS];
        }
    }
}

extern "C" void kernel_launch(void* const* d_in, const int* in_sizes, int n_in,
                              void* d_out, int out_size, void* d_ws, size_t ws_size,
                              hipStream_t stream) {
    const float* tokens = (const float*)d_in[0];
    const float* priors = (const float*)d_in[1];
    const float* rw     = (const float*)d_in[2];
    const float* rbias  = (const float*)d_in[3];
    // d_in[4..7] = w1,b1,w2,b2 : dead code (MoE output unused by reference)
    const float* ln_g   = (const float*)d_in[8];
    const float* ln_b   = (const float*)d_in[9];
    const float* cls_w  = (const float*)d_in[10];
    const float* cls_b  = (const float*)d_in[11];
    const float* aux_w  = (const float*)d_in[12];
    const float* aux_b  = (const float*)d_in[13];

    float* out = (float*)d_out;
    float* out_logits = out;                                   // 12800
    float* out_aux    = out + NB * NCLS;                       // +640
    float* out_probs  = out + NB * NCLS + NB * NORG;           // +200704
    float* out_ent    = out + NB * NCLS + NB * NORG + (size_t)NTOK * NE;

    fused_kernel<<<RBLKS + CBLKS, 256, 0, stream>>>(
        tokens, priors, rw, rbias, ln_g, ln_b, cls_w, cls_b, aux_w, aux_b,
        out_logits, out_aux, out_probs, out_ent);
}